// Round 1
// 1073.921 us; speedup vs baseline: 1.0627x; 1.0627x over previous
//
#include <hip/hip_runtime.h>
#include <hip/hip_bf16.h>

typedef __hip_bfloat16 bf16;
typedef float  f4v __attribute__((ext_vector_type(4)));
typedef unsigned int u2v __attribute__((ext_vector_type(2)));

#define SEQ   2048
#define DIM   10
#define VOC   32000
#define NROW  8192

__device__ __forceinline__ float bfr(unsigned short u) {
    return __uint_as_float(((unsigned)u) << 16);
}

// ---------------------------------------------------------------------------
// Kernel P: dtype probe, parallelized (64 lanes, ballot) instead of a serial
// 64-iteration latency chain on one thread. flag=1 -> bf16, flag=0 -> f32.
// ---------------------------------------------------------------------------
__global__ void probe_kernel(const unsigned short* __restrict__ raw,
                             int* __restrict__ flag) {
    int lane = threadIdx.x;                 // launched with 64 threads
    unsigned short u = raw[2 * lane];
    int e = (u >> 7) & 0xFF;
    int sane = (u == 0 || (e >= 97 && e <= 157)) ? 1 : 0;  // |v| in [2^-30,2^30]
    unsigned long long b = __ballot(sane != 0);
    if (lane == 0) *flag = (__popcll(b) >= 48) ? 1 : 0;
}

// ---------------------------------------------------------------------------
// Kernel 1: h = emb[x] + pos;  Q/K/V = h @ W{q,k,v}^T   (f32 to workspace)
// Unchanged: ~1 MB of traffic, far off the critical path.
// ---------------------------------------------------------------------------
__global__ __launch_bounds__(256) void qkv_kernel(
    const int* __restrict__ x, const void* __restrict__ embp,
    const void* __restrict__ posp,
    const void* __restrict__ Wqp, const void* __restrict__ Wkp,
    const void* __restrict__ Wvp, const int* __restrict__ flag,
    float* __restrict__ Q, float* __restrict__ K, float* __restrict__ V) {
    __shared__ float wq[DIM * DIM], wk[DIM * DIM], wv[DIM * DIM];
    const int isbf = *flag;
    int t = threadIdx.x;
    if (t < DIM * DIM) {
        if (isbf) {
            wq[t] = bfr(((const unsigned short*)Wqp)[t]);
            wk[t] = bfr(((const unsigned short*)Wkp)[t]);
            wv[t] = bfr(((const unsigned short*)Wvp)[t]);
        } else {
            wq[t] = ((const float*)Wqp)[t];
            wk[t] = ((const float*)Wkp)[t];
            wv[t] = ((const float*)Wvp)[t];
        }
    }
    __syncthreads();
    int row = blockIdx.x * 256 + t;     // 32 blocks * 256 = 8192 exactly
    int s = row & (SEQ - 1);
    int tok = x[row];
    float h[DIM];
    if (isbf) {
        const unsigned short* e = (const unsigned short*)embp + (size_t)tok * DIM;
        const unsigned short* p = (const unsigned short*)posp + (size_t)s * DIM;
#pragma unroll
        for (int j = 0; j < DIM; j++) h[j] = bfr(e[j]) + bfr(p[j]);
    } else {
        const float* e = (const float*)embp + (size_t)tok * DIM;
        const float* p = (const float*)posp + (size_t)s * DIM;
#pragma unroll
        for (int j = 0; j < DIM; j++) h[j] = e[j] + p[j];
    }
#pragma unroll
    for (int i = 0; i < DIM; i++) {
        float aq = 0.f, ak = 0.f, av = 0.f;
#pragma unroll
        for (int j = 0; j < DIM; j++) {
            aq += h[j] * wq[i * DIM + j];
            ak += h[j] * wk[i * DIM + j];
            av += h[j] * wv[i * DIM + j];
        }
        Q[row * DIM + i] = aq;
        K[row * DIM + i] = ak;
        V[row * DIM + i] = av;
    }
}

// ---------------------------------------------------------------------------
// Kernel 2: causal attention. 4 waves/block = 4 consecutive query rows, all in
// the same batch (512 blocks per batch). Two passes over causally-needed key
// tiles (ntiles = smax/512+1 -> ~37% work cut vs always-2048):
//   pass 1: stage K tile (512 keys) into LDS via coalesced float4, transposed
//           [d][key] so compute reads are lane-contiguous (conflict-free);
//           fill sc[32] (same key->lane mapping & FP order as before:
//           key = i*64 + lane, i = tile*8 + j -> numerically identical).
//   pass 2: same with V tiles; exp/accumulate. Masked keys stay -1e30 -> p=0.
// O may alias Q: each wave reads only its own Q row before writing O to it.
// ---------------------------------------------------------------------------
#define TK 512
__global__ __launch_bounds__(256) void attn_kernel(
    const float* __restrict__ Q, const float* __restrict__ K,
    const float* __restrict__ V, float* __restrict__ O) {
    __shared__ float kv[DIM * TK];          // transposed [d][key], 20 KB
    const int wave = threadIdx.x >> 6;
    const int lane = threadIdx.x & 63;
    const int row = blockIdx.x * 4 + wave;  // 2048 blocks * 4 = 8192
    const int b = row >> 11;
    const int s = row & (SEQ - 1);
    const int smax = (blockIdx.x * 4 + 3) & (SEQ - 1);  // max s in block
    const int ntiles = (smax >> 9) + 1;                 // tiles with live keys

    const float* qp = Q + row * DIM;
    float q[DIM];
#pragma unroll
    for (int d = 0; d < DIM; d++) q[d] = qp[d];

    const float scale = 0.3162277660168379f;  // 1/sqrt(10)
    const float* Kb = K + (size_t)(b * SEQ) * DIM;
    const float* Vb = V + (size_t)(b * SEQ) * DIM;

    float sc[32];
#pragma unroll
    for (int i = 0; i < 32; i++) sc[i] = -1e30f;

#pragma unroll
    for (int tile = 0; tile < 4; tile++) {
        if (tile < ntiles) {                 // block-uniform: syncs are safe
            __syncthreads();                 // protect previous tile's reads
            const float4* src = (const float4*)(Kb + tile * (TK * DIM));
#pragma unroll
            for (int u = 0; u < 5; u++) {    // 1280 float4 = 512 keys * 10 d
                int e4 = threadIdx.x + u * 256;
                float4 f = src[e4];
                int e = e4 * 4;              // flat element index = key*10 + d
                int r0 = (e    ) / 10, d0 = (e    ) - r0 * 10;
                int r1 = (e + 1) / 10, d1 = (e + 1) - r1 * 10;
                int r2 = (e + 2) / 10, d2 = (e + 2) - r2 * 10;
                int r3 = (e + 3) / 10, d3 = (e + 3) - r3 * 10;
                kv[d0 * TK + r0] = f.x;
                kv[d1 * TK + r1] = f.y;
                kv[d2 * TK + r2] = f.z;
                kv[d3 * TK + r3] = f.w;
            }
            __syncthreads();
#pragma unroll
            for (int j = 0; j < 8; j++) {
                int tl = (j << 6) + lane;
                int t = tile * TK + tl;
                float acc = q[0] * kv[0 * TK + tl] + q[1] * kv[1 * TK + tl] +
                            q[2] * kv[2 * TK + tl] + q[3] * kv[3 * TK + tl] +
                            q[4] * kv[4 * TK + tl] + q[5] * kv[5 * TK + tl] +
                            q[6] * kv[6 * TK + tl] + q[7] * kv[7 * TK + tl] +
                            q[8] * kv[8 * TK + tl] + q[9] * kv[9 * TK + tl];
                sc[tile * 8 + j] = (t <= s) ? acc * scale : -1e30f;
            }
        }
    }

    float m = sc[0];
#pragma unroll
    for (int i = 1; i < 32; i++) m = fmaxf(m, sc[i]);
#pragma unroll
    for (int off = 32; off; off >>= 1) m = fmaxf(m, __shfl_xor(m, off, 64));

    float sum = 0.f;
    float o[DIM];
#pragma unroll
    for (int d = 0; d < DIM; d++) o[d] = 0.f;

#pragma unroll
    for (int tile = 0; tile < 4; tile++) {
        if (tile < ntiles) {
            __syncthreads();                 // protect previous tile's reads
            const float4* src = (const float4*)(Vb + tile * (TK * DIM));
#pragma unroll
            for (int u = 0; u < 5; u++) {
                int e4 = threadIdx.x + u * 256;
                float4 f = src[e4];
                int e = e4 * 4;
                int r0 = (e    ) / 10, d0 = (e    ) - r0 * 10;
                int r1 = (e + 1) / 10, d1 = (e + 1) - r1 * 10;
                int r2 = (e + 2) / 10, d2 = (e + 2) - r2 * 10;
                int r3 = (e + 3) / 10, d3 = (e + 3) - r3 * 10;
                kv[d0 * TK + r0] = f.x;
                kv[d1 * TK + r1] = f.y;
                kv[d2 * TK + r2] = f.z;
                kv[d3 * TK + r3] = f.w;
            }
            __syncthreads();
#pragma unroll
            for (int j = 0; j < 8; j++) {
                int tl = (j << 6) + lane;
                float p = __expf(sc[tile * 8 + j] - m);  // exp(-huge)==0 masked
                sum += p;
                o[0] += p * kv[0 * TK + tl]; o[1] += p * kv[1 * TK + tl];
                o[2] += p * kv[2 * TK + tl]; o[3] += p * kv[3 * TK + tl];
                o[4] += p * kv[4 * TK + tl]; o[5] += p * kv[5 * TK + tl];
                o[6] += p * kv[6 * TK + tl]; o[7] += p * kv[7 * TK + tl];
                o[8] += p * kv[8 * TK + tl]; o[9] += p * kv[9 * TK + tl];
            }
        }
    }
#pragma unroll
    for (int off = 32; off; off >>= 1) {
        sum += __shfl_xor(sum, off, 64);
#pragma unroll
        for (int d = 0; d < DIM; d++) o[d] += __shfl_xor(o[d], off, 64);
    }
    if (lane == 0) {
        float inv = 1.0f / sum;
#pragma unroll
        for (int d = 0; d < DIM; d++) O[row * DIM + d] = o[d] * inv;
    }
}

// ---------------------------------------------------------------------------
// Kernel 3: logits = O @ Wo^T — the HBM-write bottleneck (1.048 GB f32).
// Thread t owns 4 CONTIGUOUS vocab rows (v0 = bx*1024 + t*4): Wo slice is a
// contiguous 160 B -> 10 float4 loads ONCE per block, held in 40 VGPRs and
// amortized over 64 rows (vs 8 before). Stores are lane-contiguous float4
// (1 KB/wave-instruction, full cache lines) and non-temporal so the 1 GB
// stream doesn't trash L2 for O/Wo. O-row loads are block-uniform (scalar)
// and software-pipelined one row ahead.
// ---------------------------------------------------------------------------
#define LRPB 64
__global__ __launch_bounds__(256) void logits_kernel(
    const float* __restrict__ O, const void* __restrict__ Wop,
    const int* __restrict__ flag, void* __restrict__ outp) {
    const int isbf = *flag;
    const int t = threadIdx.x;
    const int v0 = blockIdx.x * 1024 + t * 4;   // 32 x-blocks cover 32768>=32000
    if (v0 >= VOC) return;

    float w[4][DIM];
    if (isbf) {
        union { uint4 q[5]; unsigned short us[4 * DIM]; } wr;
        const uint4* p = (const uint4*)((const unsigned short*)Wop + (size_t)v0 * DIM);
#pragma unroll
        for (int k = 0; k < 5; k++) wr.q[k] = p[k];
#pragma unroll
        for (int j = 0; j < 4; j++)
#pragma unroll
            for (int d = 0; d < DIM; d++) w[j][d] = bfr(wr.us[j * DIM + d]);
    } else {
        union { float4 q[10]; float f[4 * DIM]; } wr;
        const float4* p = (const float4*)((const float*)Wop + (size_t)v0 * DIM);
#pragma unroll
        for (int k = 0; k < 10; k++) wr.q[k] = p[k];
#pragma unroll
        for (int j = 0; j < 4; j++)
#pragma unroll
            for (int d = 0; d < DIM; d++) w[j][d] = wr.f[j * DIM + d];
    }

    const int r0 = blockIdx.y * LRPB;
    float h[DIM];
#pragma unroll
    for (int d = 0; d < DIM; d++) h[d] = O[(size_t)r0 * DIM + d];

    for (int r = 0; r < LRPB; r++) {
        const int row = r0 + r;
        float hn[DIM];
        if (r + 1 < LRPB) {
#pragma unroll
            for (int d = 0; d < DIM; d++) hn[d] = O[(size_t)(row + 1) * DIM + d];
        }
        float acc0 = 0.f, acc1 = 0.f, acc2 = 0.f, acc3 = 0.f;
#pragma unroll
        for (int d = 0; d < DIM; d++) {
            acc0 += h[d] * w[0][d];
            acc1 += h[d] * w[1][d];
            acc2 += h[d] * w[2][d];
            acc3 += h[d] * w[3][d];
        }
        if (isbf) {
            union { u2v u; bf16 h4[4]; } pk;
            pk.h4[0] = __float2bfloat16(acc0);
            pk.h4[1] = __float2bfloat16(acc1);
            pk.h4[2] = __float2bfloat16(acc2);
            pk.h4[3] = __float2bfloat16(acc3);
            __builtin_nontemporal_store(
                pk.u, (u2v*)((bf16*)outp + (size_t)row * VOC + v0));
        } else {
            f4v a;
            a.x = acc0; a.y = acc1; a.z = acc2; a.w = acc3;
            __builtin_nontemporal_store(
                a, (f4v*)((float*)outp + (size_t)row * VOC + v0));
        }
        if (r + 1 < LRPB) {
#pragma unroll
            for (int d = 0; d < DIM; d++) h[d] = hn[d];
        }
    }
}

// ---------------------------------------------------------------------------
extern "C" void kernel_launch(void* const* d_in, const int* in_sizes, int n_in,
                              void* d_out, int out_size, void* d_ws, size_t ws_size,
                              hipStream_t stream) {
    const int* x = (const int*)d_in[0];
    const void* emb = d_in[1];
    const void* pos = d_in[2];
    const void* Wq  = d_in[3];
    const void* Wk  = d_in[4];
    const void* Wv  = d_in[5];
    const void* Wo  = d_in[6];

    int*   flag = (int*)d_ws;
    float* base = (float*)d_ws + 64;     // 256 B offset keeps alignment
    float* Q = base;                     // 8192*10 f32; O aliases Q (safe)
    float* K = base + 81920;
    float* V = base + 163840;
    float* O = Q;
    // total workspace use: (64 + 3*81920) * 4 B = 983,296 B

    hipLaunchKernelGGL(probe_kernel, dim3(1), dim3(64), 0, stream,
                       (const unsigned short*)emb, flag);
    hipLaunchKernelGGL(qkv_kernel, dim3(NROW / 256), dim3(256), 0, stream,
                       x, emb, pos, Wq, Wk, Wv, flag, Q, K, V);
    hipLaunchKernelGGL(attn_kernel, dim3(NROW / 4), dim3(256), 0, stream,
                       Q, K, V, O);
    hipLaunchKernelGGL(logits_kernel, dim3(32, NROW / LRPB), dim3(256), 0,
                       stream, O, Wo, flag, d_out);
}